// Round 1
// baseline (242.457 us; speedup 1.0000x reference)
//
#include <hip/hip_runtime.h>

// region_pooling via scatter + dense GEMM + split-k partials.
// F: [B=8, HW=4096, C=1024] fp32 (H=W=64); pc: [B, M=32, P=512, 2]
// out[b,m,c] = sum_hw W[b][hw][m] * F[b][hw][c]; W = scattered bilinear
// weights pre-scaled by 1/P.
//
// v2: wgemm reads W via wave-uniform loads (-> s_load into SGPRs) instead of
// LDS broadcast storm; 2 channels/thread via float2 F loads. No LDS in wgemm.

#define NB 8
#define NM 32
#define NP 512
#define NC 1024
#define NH 64
#define NHW 4096

#define KC    128                 // hw per k-chunk
#define NKC   (NHW / KC)          // 32 k-chunks
#define CPT   2                   // channels per thread
#define CT    256                 // threads per block
#define CTILE (CT * CPT)          // 512 channels per block
#define NCT   (NC / CTILE)        // 2 c-tiles
#define PF    8                   // F prefetch depth (float2 each)

// ---- Phase 1: scatter bilinear weights into W[b][hw][m] (pre-zeroed) ----
__global__ __launch_bounds__(256) void scatter_w(
    const float* __restrict__ pc, float* __restrict__ W)
{
    int idx = blockIdx.x * 256 + threadIdx.x;   // [0, B*M*P)
    int bm  = idx >> 9;                         // b*NM + m
    int m   = bm & (NM - 1);
    int b   = bm >> 5;

    float2 c = ((const float2*)pc)[idx];
    float y = c.x * 63.0f;
    float x = c.y * 63.0f;
    float x0f = floorf(x), y0f = floorf(y);
    float wx = x - x0f, wy = y - y0f;
    int ix0 = min(max((int)x0f, 0), 63);
    int ix1 = min(ix0 + 1, 63);
    int iy0 = min(max((int)y0f, 0), 63);
    int iy1 = min(iy0 + 1, 63);
    float wx1 = 1.0f - wx, wy1 = 1.0f - wy;
    const float s = 1.0f / (float)NP;           // fold the mean here

    float* Wb = W + (size_t)b * (NHW * NM) + m;
    atomicAdd(Wb + ((iy0 * NH + ix0) * NM), wx1 * wy1 * s);
    atomicAdd(Wb + ((iy0 * NH + ix1) * NM), wx  * wy1 * s);
    atomicAdd(Wb + ((iy1 * NH + ix0) * NM), wx1 * wy  * s);
    atomicAdd(Wb + ((iy1 * NH + ix1) * NM), wx  * wy  * s);
}

// ---- Phase 2: P[kc][b][m][c] = sum_{hw in chunk kc} W[b][hw][m]*F[b][hw][c]
// Grid (NKC, NCT, NB) = (32, 2, 8) = 512 blocks, 256 thr: 2 blocks/CU.
// W addresses are wave-uniform (blockIdx + loop-var only) -> scalar loads
// into SGPRs; FMA reads w straight from SGPR (1 sgpr/VALU op is legal).
// F loaded as float2 (2 channels/thread), prefetched PF deep.
__global__ __launch_bounds__(256, 2) void wgemm(
    const float* __restrict__ W, const float* __restrict__ F,
    float* __restrict__ P)
{
    const int kc  = blockIdx.x;                 // 32 k-chunks
    const int ct  = blockIdx.y;                 // 2 c-tiles
    const int b   = blockIdx.z;
    const int tid = threadIdx.x;
    const int c   = ct * CTILE + tid * CPT;
    const int hw0 = kc * KC;

    // W chunk for this (b, kc): KC x NM floats, uniform across the block.
    const float4* __restrict__ Wk =
        (const float4*)(W + ((size_t)b * NHW + hw0) * NM);   // [KC * NM/4]

    const float2* __restrict__ Fb =
        (const float2*)(F + ((size_t)b * NHW + hw0) * NC + c);
    const int fstride = NC / 2;                 // float2 stride per hw

    float accx[NM], accy[NM];
#pragma unroll
    for (int m = 0; m < NM; ++m) { accx[m] = 0.0f; accy[m] = 0.0f; }

    float2 fbuf[PF];
#pragma unroll
    for (int j = 0; j < PF; ++j) fbuf[j] = Fb[(size_t)j * fstride];

    for (int i = 0; i < KC; i += PF) {
        float2 fcur[PF];
#pragma unroll
        for (int j = 0; j < PF; ++j) fcur[j] = fbuf[j];
        if (i + PF < KC) {
#pragma unroll
            for (int j = 0; j < PF; ++j)
                fbuf[j] = Fb[(size_t)(i + PF + j) * fstride];
        }
#pragma unroll
        for (int j = 0; j < PF; ++j) {
            const float4* __restrict__ w4 = Wk + (i + j) * (NM / 4);
            float2 f = fcur[j];
#pragma unroll
            for (int q = 0; q < NM / 4; ++q) {
                float4 w = w4[q];               // uniform -> SGPRs
                accx[q * 4 + 0] = fmaf(w.x, f.x, accx[q * 4 + 0]);
                accy[q * 4 + 0] = fmaf(w.x, f.y, accy[q * 4 + 0]);
                accx[q * 4 + 1] = fmaf(w.y, f.x, accx[q * 4 + 1]);
                accy[q * 4 + 1] = fmaf(w.y, f.y, accy[q * 4 + 1]);
                accx[q * 4 + 2] = fmaf(w.z, f.x, accx[q * 4 + 2]);
                accy[q * 4 + 2] = fmaf(w.z, f.y, accy[q * 4 + 2]);
                accx[q * 4 + 3] = fmaf(w.w, f.x, accx[q * 4 + 3]);
                accy[q * 4 + 3] = fmaf(w.w, f.y, accy[q * 4 + 3]);
            }
        }
    }

    // partials: P[((kc*NB + b)*NM + m)*NC + c], float2 per m
    float* pb = P + (((size_t)kc * NB + b) * NM) * NC + c;
#pragma unroll
    for (int m = 0; m < NM; ++m)
        *(float2*)(pb + (size_t)m * NC) = make_float2(accx[m], accy[m]);
}

// ---- Phase 3: out = sum over the 32 k-chunk partials ----
__global__ __launch_bounds__(256) void reduce_p(
    const float* __restrict__ P, float* __restrict__ out)
{
    const int idx = blockIdx.x * 256 + threadIdx.x;   // [0, NB*NM*NC/4)
    const float4* p4 = (const float4*)P;
    const int stride = NB * NM * NC / 4;              // 65536
    float4 s = make_float4(0.f, 0.f, 0.f, 0.f);
#pragma unroll
    for (int kc = 0; kc < NKC; ++kc) {
        float4 v = p4[(size_t)kc * stride + idx];
        s.x += v.x; s.y += v.y; s.z += v.z; s.w += v.w;
    }
    ((float4*)out)[idx] = s;
}

// ---- Fallback (ws too small): direct gather ----
__global__ __launch_bounds__(256) void region_pool_direct(
    const float* __restrict__ fm, const float* __restrict__ pc,
    float* __restrict__ out)
{
    __shared__ int4   sIdx[NP];
    __shared__ float4 sWt[NP];
    const int bid = blockIdx.x;
    const int b   = bid >> 5;
    const int tid = threadIdx.x;
    const float2* pc2 = (const float2*)(pc + (size_t)bid * NP * 2);
    for (int p = tid; p < NP; p += 256) {
        float2 c = pc2[p];
        float y = c.x * 63.0f, x = c.y * 63.0f;
        float x0f = floorf(x), y0f = floorf(y);
        float wx = x - x0f, wy = y - y0f;
        int ix0 = min(max((int)x0f, 0), 63);
        int ix1 = min(ix0 + 1, 63);
        int iy0 = min(max((int)y0f, 0), 63);
        int iy1 = min(iy0 + 1, 63);
        sIdx[p] = make_int4((iy0 * NH + ix0) << 10, (iy0 * NH + ix1) << 10,
                            (iy1 * NH + ix0) << 10, (iy1 * NH + ix1) << 10);
        float wx1 = 1.0f - wx, wy1 = 1.0f - wy;
        sWt[p] = make_float4(wx1 * wy1, wx * wy1, wx1 * wy, wx * wy);
    }
    __syncthreads();
    const float* Fb = fm + (size_t)b * (NHW * NC) + tid * 4;
    float4 acc = make_float4(0.f, 0.f, 0.f, 0.f);
#pragma unroll 4
    for (int p = 0; p < NP; ++p) {
        int4 off = sIdx[p]; float4 w = sWt[p];
        float4 f00 = *(const float4*)(Fb + off.x);
        float4 f01 = *(const float4*)(Fb + off.y);
        float4 f10 = *(const float4*)(Fb + off.z);
        float4 f11 = *(const float4*)(Fb + off.w);
        acc.x = fmaf(w.x, f00.x, fmaf(w.y, f01.x, fmaf(w.z, f10.x, fmaf(w.w, f11.x, acc.x))));
        acc.y = fmaf(w.x, f00.y, fmaf(w.y, f01.y, fmaf(w.z, f10.y, fmaf(w.w, f11.y, acc.y))));
        acc.z = fmaf(w.x, f00.z, fmaf(w.y, f01.z, fmaf(w.z, f10.z, fmaf(w.w, f11.z, acc.z))));
        acc.w = fmaf(w.x, f00.w, fmaf(w.y, f01.w, fmaf(w.z, f10.w, fmaf(w.w, f11.w, acc.w))));
    }
    const float inv = 1.0f / (float)NP;
    ((float4*)(out + (size_t)bid * NC))[tid] =
        make_float4(acc.x * inv, acc.y * inv, acc.z * inv, acc.w * inv);
}

extern "C" void kernel_launch(void* const* d_in, const int* in_sizes, int n_in,
                              void* d_out, int out_size, void* d_ws, size_t ws_size,
                              hipStream_t stream) {
    const float* fm = (const float*)d_in[0];   // [8, 4096, 1024]
    const float* pc = (const float*)d_in[1];   // [8, 32, 512, 2]
    float* out = (float*)d_out;                // [8, 32, 1, 1024]

    const size_t wbytes = (size_t)NB * NHW * NM * sizeof(float);           // 4 MB
    const size_t pbytes = (size_t)NKC * NB * NM * NC * sizeof(float);      // 32 MB
    if (ws_size >= wbytes + pbytes) {
        float* W = (float*)d_ws;
        float* P = (float*)((char*)d_ws + wbytes);
        hipMemsetAsync(W, 0, wbytes, stream);
        scatter_w<<<(NB * NM * NP) / 256, 256, 0, stream>>>(pc, W);
        dim3 grid(NKC, NCT, NB);
        wgemm<<<grid, CT, 0, stream>>>(W, fm, P);
        reduce_p<<<(NB * NM * NC / 4) / 256, 256, 0, stream>>>(P, out);
    } else {
        region_pool_direct<<<NB * NM, 256, 0, stream>>>(fm, pc, out);
    }
}

// Round 2
// 238.755 us; speedup vs baseline: 1.0155x; 1.0155x over previous
//
#include <hip/hip_runtime.h>
#include <stdint.h>

// region_pooling via scatter + dense GEMM + split-k partials.
// F: [B=8, HW=4096, C=1024] fp32 (H=W=64); pc: [B, M=32, P=512, 2]
// out[b,m,c] = sum_hw W[b][hw][m] * F[b][hw][c]; W = scattered bilinear
// weights pre-scaled by 1/P.
//
// v3: W reads forced onto the SCALAR pipe via address_space(4) (constant)
// pointer -> s_load_dwordx4 through K$. Inner loop VMEM = F loads only.

#define NB 8
#define NM 32
#define NP 512
#define NC 1024
#define NH 64
#define NHW 4096

#define KC    128                 // hw per k-chunk
#define NKC   (NHW / KC)          // 32 k-chunks
#define CPT   2                   // channels per thread
#define CT    256                 // threads per block
#define CTILE (CT * CPT)          // 512 channels per block
#define NCT   (NC / CTILE)        // 2 c-tiles
#define PF    8                   // F prefetch depth (float2 each)

typedef float f4 __attribute__((ext_vector_type(4)));
#define AS4 __attribute__((address_space(4)))

// ---- Phase 1: scatter bilinear weights into W[b][hw][m] (pre-zeroed) ----
__global__ __launch_bounds__(256) void scatter_w(
    const float* __restrict__ pc, float* __restrict__ W)
{
    int idx = blockIdx.x * 256 + threadIdx.x;   // [0, B*M*P)
    int bm  = idx >> 9;                         // b*NM + m
    int m   = bm & (NM - 1);
    int b   = bm >> 5;

    float2 c = ((const float2*)pc)[idx];
    float y = c.x * 63.0f;
    float x = c.y * 63.0f;
    float x0f = floorf(x), y0f = floorf(y);
    float wx = x - x0f, wy = y - y0f;
    int ix0 = min(max((int)x0f, 0), 63);
    int ix1 = min(ix0 + 1, 63);
    int iy0 = min(max((int)y0f, 0), 63);
    int iy1 = min(iy0 + 1, 63);
    float wx1 = 1.0f - wx, wy1 = 1.0f - wy;
    const float s = 1.0f / (float)NP;           // fold the mean here

    float* Wb = W + (size_t)b * (NHW * NM) + m;
    atomicAdd(Wb + ((iy0 * NH + ix0) * NM), wx1 * wy1 * s);
    atomicAdd(Wb + ((iy0 * NH + ix1) * NM), wx  * wy1 * s);
    atomicAdd(Wb + ((iy1 * NH + ix0) * NM), wx1 * wy  * s);
    atomicAdd(Wb + ((iy1 * NH + ix1) * NM), wx  * wy  * s);
}

// ---- Phase 2: P[kc][b][m][c] = sum_{hw in chunk kc} W[b][hw][m]*F[b][hw][c]
// Grid (NKC, NCT, NB) = (32, 2, 8) = 512 blocks, 256 thr: 2 blocks/CU.
// W chunk pointer cast to constant addrspace(4): uniform address ->
// s_load_dwordx4 on the scalar pipe; FMA uses the SGPR operand directly.
__global__ __launch_bounds__(256, 2) void wgemm(
    const float* __restrict__ W, const float* __restrict__ F,
    float* __restrict__ P)
{
    const int kc  = blockIdx.x;                 // 32 k-chunks
    const int ct  = blockIdx.y;                 // 2 c-tiles
    const int b   = blockIdx.z;
    const int tid = threadIdx.x;
    const int c   = ct * CTILE + tid * CPT;
    const int hw0 = kc * KC;

    // W chunk for this (b, kc): KC x NM floats, wave-uniform -> scalar loads.
    const AS4 f4* __restrict__ Wc =
        (const AS4 f4*)(uintptr_t)(W + ((size_t)b * NHW + hw0) * NM);

    const float2* __restrict__ Fb =
        (const float2*)(F + ((size_t)b * NHW + hw0) * NC + c);
    const int fstride = NC / 2;                 // float2 stride per hw

    float accx[NM], accy[NM];
#pragma unroll
    for (int m = 0; m < NM; ++m) { accx[m] = 0.0f; accy[m] = 0.0f; }

    float2 fbuf[PF];
#pragma unroll
    for (int j = 0; j < PF; ++j) fbuf[j] = Fb[(size_t)j * fstride];

    for (int i = 0; i < KC; i += PF) {
        float2 fcur[PF];
#pragma unroll
        for (int j = 0; j < PF; ++j) fcur[j] = fbuf[j];
        if (i + PF < KC) {
#pragma unroll
            for (int j = 0; j < PF; ++j)
                fbuf[j] = Fb[(size_t)(i + PF + j) * fstride];
        }
#pragma unroll
        for (int j = 0; j < PF; ++j) {
            const AS4 f4* __restrict__ w4 = Wc + (i + j) * (NM / 4);
            float2 f = fcur[j];
#pragma unroll
            for (int q = 0; q < NM / 4; ++q) {
                f4 w = w4[q];                   // s_load_dwordx4 (uniform)
                accx[q * 4 + 0] = fmaf(w.x, f.x, accx[q * 4 + 0]);
                accy[q * 4 + 0] = fmaf(w.x, f.y, accy[q * 4 + 0]);
                accx[q * 4 + 1] = fmaf(w.y, f.x, accx[q * 4 + 1]);
                accy[q * 4 + 1] = fmaf(w.y, f.y, accy[q * 4 + 1]);
                accx[q * 4 + 2] = fmaf(w.z, f.x, accx[q * 4 + 2]);
                accy[q * 4 + 2] = fmaf(w.z, f.y, accy[q * 4 + 2]);
                accx[q * 4 + 3] = fmaf(w.w, f.x, accx[q * 4 + 3]);
                accy[q * 4 + 3] = fmaf(w.w, f.y, accy[q * 4 + 3]);
            }
        }
    }

    // partials: P[((kc*NB + b)*NM + m)*NC + c], float2 per m
    float* pb = P + (((size_t)kc * NB + b) * NM) * NC + c;
#pragma unroll
    for (int m = 0; m < NM; ++m)
        *(float2*)(pb + (size_t)m * NC) = make_float2(accx[m], accy[m]);
}

// ---- Phase 3: out = sum over the 32 k-chunk partials ----
__global__ __launch_bounds__(256) void reduce_p(
    const float* __restrict__ P, float* __restrict__ out)
{
    const int idx = blockIdx.x * 256 + threadIdx.x;   // [0, NB*NM*NC/4)
    const float4* p4 = (const float4*)P;
    const int stride = NB * NM * NC / 4;              // 65536
    float4 s = make_float4(0.f, 0.f, 0.f, 0.f);
#pragma unroll
    for (int kc = 0; kc < NKC; ++kc) {
        float4 v = p4[(size_t)kc * stride + idx];
        s.x += v.x; s.y += v.y; s.z += v.z; s.w += v.w;
    }
    ((float4*)out)[idx] = s;
}

// ---- Fallback (ws too small): direct gather ----
__global__ __launch_bounds__(256) void region_pool_direct(
    const float* __restrict__ fm, const float* __restrict__ pc,
    float* __restrict__ out)
{
    __shared__ int4   sIdx[NP];
    __shared__ float4 sWt[NP];
    const int bid = blockIdx.x;
    const int b   = bid >> 5;
    const int tid = threadIdx.x;
    const float2* pc2 = (const float2*)(pc + (size_t)bid * NP * 2);
    for (int p = tid; p < NP; p += 256) {
        float2 c = pc2[p];
        float y = c.x * 63.0f, x = c.y * 63.0f;
        float x0f = floorf(x), y0f = floorf(y);
        float wx = x - x0f, wy = y - y0f;
        int ix0 = min(max((int)x0f, 0), 63);
        int ix1 = min(ix0 + 1, 63);
        int iy0 = min(max((int)y0f, 0), 63);
        int iy1 = min(iy0 + 1, 63);
        sIdx[p] = make_int4((iy0 * NH + ix0) << 10, (iy0 * NH + ix1) << 10,
                            (iy1 * NH + ix0) << 10, (iy1 * NH + ix1) << 10);
        float wx1 = 1.0f - wx, wy1 = 1.0f - wy;
        sWt[p] = make_float4(wx1 * wy1, wx * wy1, wx1 * wy, wx * wy);
    }
    __syncthreads();
    const float* Fb = fm + (size_t)b * (NHW * NC) + tid * 4;
    float4 acc = make_float4(0.f, 0.f, 0.f, 0.f);
#pragma unroll 4
    for (int p = 0; p < NP; ++p) {
        int4 off = sIdx[p]; float4 w = sWt[p];
        float4 f00 = *(const float4*)(Fb + off.x);
        float4 f01 = *(const float4*)(Fb + off.y);
        float4 f10 = *(const float4*)(Fb + off.z);
        float4 f11 = *(const float4*)(Fb + off.w);
        acc.x = fmaf(w.x, f00.x, fmaf(w.y, f01.x, fmaf(w.z, f10.x, fmaf(w.w, f11.x, acc.x))));
        acc.y = fmaf(w.x, f00.y, fmaf(w.y, f01.y, fmaf(w.z, f10.y, fmaf(w.w, f11.y, acc.y))));
        acc.z = fmaf(w.x, f00.z, fmaf(w.y, f01.z, fmaf(w.z, f10.z, fmaf(w.w, f11.z, acc.z))));
        acc.w = fmaf(w.x, f00.w, fmaf(w.y, f01.w, fmaf(w.z, f10.w, fmaf(w.w, f11.w, acc.w))));
    }
    const float inv = 1.0f / (float)NP;
    ((float4*)(out + (size_t)bid * NC))[tid] =
        make_float4(acc.x * inv, acc.y * inv, acc.z * inv, acc.w * inv);
}

extern "C" void kernel_launch(void* const* d_in, const int* in_sizes, int n_in,
                              void* d_out, int out_size, void* d_ws, size_t ws_size,
                              hipStream_t stream) {
    const float* fm = (const float*)d_in[0];   // [8, 4096, 1024]
    const float* pc = (const float*)d_in[1];   // [8, 32, 512, 2]
    float* out = (float*)d_out;                // [8, 32, 1, 1024]

    const size_t wbytes = (size_t)NB * NHW * NM * sizeof(float);           // 4 MB
    const size_t pbytes = (size_t)NKC * NB * NM * NC * sizeof(float);      // 32 MB
    if (ws_size >= wbytes + pbytes) {
        float* W = (float*)d_ws;
        float* P = (float*)((char*)d_ws + wbytes);
        hipMemsetAsync(W, 0, wbytes, stream);
        scatter_w<<<(NB * NM * NP) / 256, 256, 0, stream>>>(pc, W);
        dim3 grid(NKC, NCT, NB);
        wgemm<<<grid, CT, 0, stream>>>(W, fm, P);
        reduce_p<<<(NB * NM * NC / 4) / 256, 256, 0, stream>>>(P, out);
    } else {
        region_pool_direct<<<NB * NM, 256, 0, stream>>>(fm, pc, out);
    }
}